// Round 9
// baseline (237.558 us; speedup 1.0000x reference)
//
#include <hip/hip_runtime.h>

// ---------------------------------------------------------------------------
// AttentionDecoder: B=64, S=512, H=1024, V=32000
// outputs (f32, concat): output [64,32000] | h_new [64,1024] | attn_w [64,512]
// ---------------------------------------------------------------------------

typedef __bf16 bf16;
typedef __attribute__((ext_vector_type(4))) float  f32x4;
typedef __attribute__((ext_vector_type(4))) float  fx4;
typedef __attribute__((ext_vector_type(8))) bf16   bf16x8;
typedef __attribute__((ext_vector_type(4))) bf16   bf16x4;
typedef __attribute__((ext_vector_type(4))) unsigned int u32x4;
typedef __attribute__((ext_vector_type(2))) unsigned int u32x2;

#define MFMA16x16x32(a, b, c) __builtin_amdgcn_mfma_f32_16x16x32_bf16(a, b, c, 0, 0, 0)

#define Bb   64
#define Ss   512
#define Hh   1024
#define Vv   32000
#define Mtot (Bb * Ss)          // 32768

// ---- d_ws layout (bytes) --------------------------------------------------
#define WS_HNEW_B    131072                  // 64*1024 bf16   = 128KB
#define WS_XC_B      262144                  // 64*2048 bf16   = 256KB
#define WS_W1A_B     524288                  // 1024*1024 bf16 = 2MB
#define WS_P_HB      2621440                 // [4][64][1024] f32 = 1MB
#define WS_P_HZ      3670016
#define WS_P_HN      4718592
#define WS_P_IZ      5767168
#define WS_P_IR      6815744
#define WS_P_IN      7864320
#define WS_SCORES    8912896                 // [16][32768] f32 = 2MB
#define WS_CTX       11010048                // [8][64][1024] f32 = 2MB
#define WS_ANNB      13107200                // 32768*1024 bf16 = 64MB
// total ~80.3MB

// ---- d_out offsets (floats) ----------------------------------------------
#define OUT_LOGITS   0
#define OUT_HNEW     2048000
#define OUT_AW       2113536

__device__ __forceinline__ float bf2f(unsigned short u) {
    unsigned int x = ((unsigned int)u) << 16;
    float f;
    __builtin_memcpy(&f, &x, 4);
    return f;
}

// async global->LDS, 16B per lane. LDS dest is wave-uniform base; HW writes
// base + lane*16.
__device__ __forceinline__ void gload_lds16(const bf16* g, bf16* l)
{
    __builtin_amdgcn_global_load_lds(
        (const __attribute__((address_space(1))) unsigned int*)g,
        (__attribute__((address_space(3))) unsigned int*)l,
        16, 0, 0);
}

// ===========================================================================
// k_pre: merged pre-attention work, role-split grid (3328 blocks x 256):
//  [0,192)    : M=64 GEMM  p_hB/p_hz/p_hn = h_prev(f32) @ {W1b,W_hz,W_hn}^T
//  [192,1280) : prep: embed gather -> xc_b[:,H:2H] ; W1a -> bf16
//  [1280,3328): convann: ann f32 -> annb bf16 (201MB stream, hides the rest)
// ===========================================================================
__global__ __launch_bounds__(256, 2) void k_pre(
    const int* __restrict__ x, const float* __restrict__ h_prev,
    const float* __restrict__ emb, const float* __restrict__ attn_W1,
    const float* __restrict__ W_hz, const float* __restrict__ W_hn,
    const float* __restrict__ ann,
    bf16* __restrict__ xc_b, bf16* __restrict__ W1a_b, bf16* __restrict__ annb,
    float* __restrict__ p_hB, float* __restrict__ p_hz, float* __restrict__ p_hn)
{
    __shared__ __align__(16) bf16 lA[2][64][72];
    __shared__ __align__(16) bf16 lB[2][64][72];

    int bid = blockIdx.x, t = threadIdx.x;

    if (bid >= 1280) {
        // ---- convann ----
        size_t i = ((size_t)(bid - 1280) * 256 + t) * 8;
        size_t stride = (size_t)2048 * 256 * 8;
        size_t n = (size_t)Mtot * Hh;
        for (; i < n; i += stride) {
            fx4 v0 = *(const fx4*)(ann + i);
            fx4 v1 = *(const fx4*)(ann + i + 4);
            bf16x8 o;
#pragma unroll
            for (int q = 0; q < 4; q++) { o[q] = (bf16)v0[q]; o[q + 4] = (bf16)v1[q]; }
            *(bf16x8*)(annb + i) = o;
        }
        return;
    }
    if (bid >= 192) {
        // ---- prep ----
        int sub = bid - 192;
        if (sub < 64) {
            int b = sub, row = x[b];
            for (int i = t; i < Hh; i += 256)
                xc_b[b * 2048 + Hh + i] = (bf16)emb[(size_t)row * Hh + i];
        } else {
            int row = sub - 64;
            int k4 = t * 4;
            fx4 v = *(const fx4*)(attn_W1 + (size_t)row * 2048 + k4);
            bf16x4 o;
#pragma unroll
            for (int q = 0; q < 4; q++) o[q] = (bf16)v[q];
            *(bf16x4*)(W1a_b + (size_t)row * Hh + k4) = o;
        }
        return;
    }

    // ---- M=64 GEMM role (f32 A = h_prev) ----
    int nb = bid & 15, sk = (bid >> 4) & 3, mat = bid >> 6;
    const float* Bp = (mat == 0) ? (attn_W1 + 1024) : (mat == 1 ? W_hz : W_hn);
    int ldb         = (mat == 0) ? 2048 : 1024;
    float* op       = (mat == 0) ? p_hB : (mat == 1 ? p_hz : p_hn);

    int n0 = nb * 64, k0 = sk * 256;
    int lane = t & 63, wid = t >> 6;
    int srow = t >> 2, schunk = t & 3;

    const float* agp = h_prev + (size_t)srow * 1024 + k0 + schunk * 16;
    const float* bgp = Bp + (size_t)(n0 + srow) * ldb + k0 + schunk * 16;

    f32x4 acc[4];
#pragma unroll
    for (int i = 0; i < 4; i++) acc[i] = (f32x4)0.0f;

    fx4 aRf[4], bRf[4];
#pragma unroll
    for (int q = 0; q < 4; q++) { aRf[q] = *(const fx4*)(agp + q * 4);
                                  bRf[q] = *(const fx4*)(bgp + q * 4); }
    {
        bf16x8 a0, a1, p0, p1;
#pragma unroll
        for (int q = 0; q < 4; q++) {
            a0[q] = (bf16)aRf[0][q]; a0[q + 4] = (bf16)aRf[1][q];
            a1[q] = (bf16)aRf[2][q]; a1[q + 4] = (bf16)aRf[3][q];
            p0[q] = (bf16)bRf[0][q]; p0[q + 4] = (bf16)bRf[1][q];
            p1[q] = (bf16)bRf[2][q]; p1[q + 4] = (bf16)bRf[3][q];
        }
        *(bf16x8*)&lA[0][srow][schunk * 16]     = a0;
        *(bf16x8*)&lA[0][srow][schunk * 16 + 8] = a1;
        *(bf16x8*)&lB[0][srow][schunk * 16]     = p0;
        *(bf16x8*)&lB[0][srow][schunk * 16 + 8] = p1;
    }
    __syncthreads();

    int cur = 0;
    for (int ks = 0; ks < 4; ks++) {
        if (ks + 1 < 4) {
#pragma unroll
            for (int q = 0; q < 4; q++) {
                aRf[q] = *(const fx4*)(agp + (ks + 1) * 64 + q * 4);
                bRf[q] = *(const fx4*)(bgp + (ks + 1) * 64 + q * 4);
            }
        }
        int rA = lane & 15;
        int kc = (lane >> 4) * 8;
#pragma unroll
        for (int kk = 0; kk < 2; kk++) {
            bf16x8 bfr = *(bf16x8*)&lB[cur][wid * 16 + rA][kk * 32 + kc];
#pragma unroll
            for (int i = 0; i < 4; i++) {
                bf16x8 af = *(bf16x8*)&lA[cur][i * 16 + rA][kk * 32 + kc];
                acc[i] = MFMA16x16x32(af, bfr, acc[i]);
            }
        }
        if (ks + 1 < 4) {
            int nxt = cur ^ 1;
            bf16x8 a0, a1, p0, p1;
#pragma unroll
            for (int q = 0; q < 4; q++) {
                a0[q] = (bf16)aRf[0][q]; a0[q + 4] = (bf16)aRf[1][q];
                a1[q] = (bf16)aRf[2][q]; a1[q + 4] = (bf16)aRf[3][q];
                p0[q] = (bf16)bRf[0][q]; p0[q + 4] = (bf16)bRf[1][q];
                p1[q] = (bf16)bRf[2][q]; p1[q + 4] = (bf16)bRf[3][q];
            }
            *(bf16x8*)&lA[nxt][srow][schunk * 16]     = a0;
            *(bf16x8*)&lA[nxt][srow][schunk * 16 + 8] = a1;
            *(bf16x8*)&lB[nxt][srow][schunk * 16]     = p0;
            *(bf16x8*)&lB[nxt][srow][schunk * 16 + 8] = p1;
        }
        __syncthreads();
        cur ^= 1;
    }

    int n = n0 + wid * 16 + (lane & 15);
#pragma unroll
    for (int i = 0; i < 4; i++)
#pragma unroll
        for (int r = 0; r < 4; r++) {
            int m = i * 16 + (lane >> 4) * 4 + r;
            op[(size_t)(sk * 64 + m) * 1024 + n] = acc[i][r];
        }
}

// ===========================================================================
// k_sgemm: M=64 GEMM, out[m][n] = sum_k A_bf16[m][k] * (f32)Bmat[n][k]
// tile BM=64 BN=64 BK=64, 4 waves, dbuf reg-staged. (gates + W_out)
// ===========================================================================
__global__ __launch_bounds__(256, 2) void k_sgemm(
    const bf16* __restrict__ A, int lda, int kchunk,
    const float* __restrict__ B0, const float* __restrict__ B1, const float* __restrict__ B2,
    int ldb0, int ldb1, int ldb2,
    float* __restrict__ o0, float* __restrict__ o1, float* __restrict__ o2,
    const float* __restrict__ bias, int N, int finalOut)
{
    __shared__ __align__(16) bf16 lA[2][64][72];
    __shared__ __align__(16) bf16 lB[2][64][72];

    int nb = blockIdx.x, sk = blockIdx.y, mat = blockIdx.z;
    const float* Bp = (mat == 0) ? B0 : (mat == 1 ? B1 : B2);
    int ldb         = (mat == 0) ? ldb0 : (mat == 1 ? ldb1 : ldb2);
    float* op       = (mat == 0) ? o0 : (mat == 1 ? o1 : o2);

    int n0 = nb * 64, k0 = sk * kchunk;
    int t = threadIdx.x, lane = t & 63, wid = t >> 6;
    int srow = t >> 2, schunk = t & 3;

    const bf16*  agp = A  + (size_t)srow * lda + k0 + schunk * 16;
    const float* bgp = Bp + (size_t)(n0 + srow) * ldb + k0 + schunk * 16;

    f32x4 acc[4];
#pragma unroll
    for (int i = 0; i < 4; i++) acc[i] = (f32x4)0.0f;

    u32x4 aR0, aR1; fx4 bRf[4];
    int nk = kchunk >> 6;

    aR0 = *(const u32x4*)(agp);
    aR1 = *(const u32x4*)(agp + 8);
#pragma unroll
    for (int q = 0; q < 4; q++) bRf[q] = *(const fx4*)(bgp + q * 4);
    {
        *(u32x4*)&lA[0][srow][schunk * 16]     = aR0;
        *(u32x4*)&lA[0][srow][schunk * 16 + 8] = aR1;
        bf16x8 p0, p1;
#pragma unroll
        for (int q = 0; q < 4; q++) {
            p0[q] = (bf16)bRf[0][q]; p0[q + 4] = (bf16)bRf[1][q];
            p1[q] = (bf16)bRf[2][q]; p1[q + 4] = (bf16)bRf[3][q];
        }
        *(bf16x8*)&lB[0][srow][schunk * 16]     = p0;
        *(bf16x8*)&lB[0][srow][schunk * 16 + 8] = p1;
    }
    __syncthreads();

    int cur = 0;
    for (int ks = 0; ks < nk; ks++) {
        if (ks + 1 < nk) {
            aR0 = *(const u32x4*)(agp + (ks + 1) * 64);
            aR1 = *(const u32x4*)(agp + (ks + 1) * 64 + 8);
#pragma unroll
            for (int q = 0; q < 4; q++) bRf[q] = *(const fx4*)(bgp + (ks + 1) * 64 + q * 4);
        }
        int rA = lane & 15;
        int kc = (lane >> 4) * 8;
#pragma unroll
        for (int kk = 0; kk < 2; kk++) {
            bf16x8 bfr = *(bf16x8*)&lB[cur][wid * 16 + rA][kk * 32 + kc];
#pragma unroll
            for (int i = 0; i < 4; i++) {
                bf16x8 af = *(bf16x8*)&lA[cur][i * 16 + rA][kk * 32 + kc];
                acc[i] = MFMA16x16x32(af, bfr, acc[i]);
            }
        }
        if (ks + 1 < nk) {
            int nxt = cur ^ 1;
            *(u32x4*)&lA[nxt][srow][schunk * 16]     = aR0;
            *(u32x4*)&lA[nxt][srow][schunk * 16 + 8] = aR1;
            bf16x8 p0, p1;
#pragma unroll
            for (int q = 0; q < 4; q++) {
                p0[q] = (bf16)bRf[0][q]; p0[q + 4] = (bf16)bRf[1][q];
                p1[q] = (bf16)bRf[2][q]; p1[q + 4] = (bf16)bRf[3][q];
            }
            *(bf16x8*)&lB[nxt][srow][schunk * 16]     = p0;
            *(bf16x8*)&lB[nxt][srow][schunk * 16 + 8] = p1;
        }
        __syncthreads();
        cur ^= 1;
    }

    int n = n0 + wid * 16 + (lane & 15);
#pragma unroll
    for (int i = 0; i < 4; i++) {
#pragma unroll
        for (int r = 0; r < 4; r++) {
            int m = i * 16 + (lane >> 4) * 4 + r;
            float v = acc[i][r];
            if (finalOut) op[(size_t)m * N + n] = v + bias[n];
            else          op[(size_t)(sk * 64 + m) * N + n] = v;
        }
    }
}

// ===========================================================================
// k_attn v9: 256x256, BK=64, 8 waves. A = REGISTER-DIRECT from global
// (per-lane dwordx4, L2-served; no A LDS round trip -> LDS reads cut 3x).
// B (W1a) via global_load_lds into double-buffered 64KB LDS, chunk-XOR
// swizzle c ^= (row&7) (both sides, v6-verified). ONE barrier per K-tile;
// waves drift between barriers -> LDS/VMEM/matrix overlap across waves.
// A prefetch: AQC holds IH0(kt) (loaded last tile), AQN <- IH1(kt) at P0,
// AQC <- IH0(kt+1) after P1. Tile end: sched_barrier + vmcnt(8) (exactly
// the 8 next-tile A-loads outstanding -> B staging drained) + s_barrier.
// Fused epilogue: relu(hA+hB+b1)*W2 -> scores_part[nbp*4+wn][m].
// ===========================================================================
__global__ __launch_bounds__(512, 2) void k_attn(
    const bf16* __restrict__ annb, const bf16* __restrict__ Bw,
    const float* __restrict__ p_hB, const float* __restrict__ b1v,
    const float* __restrict__ W2, float* __restrict__ scores_part)
{
    extern __shared__ char smem[];               // [2 bufs][2 halves][128][64] bf16

    int bid = blockIdx.x;
    int wgid = (bid & 7) * 64 + (bid >> 3);      // XCD-contiguous (512%8==0)
    int mb = wgid >> 2, nbp = wgid & 3;

    int t = threadIdx.x, lane = t & 63, wid = t >> 6;
    int wm = wid >> 2, wn = wid & 3;
    int r = lane & 15, q = lane >> 4;

    // ---- B staging constants (linear LDS dest, inverse-swizzled source) ----
    int srow = t >> 3;
    int gc = (t & 7) ^ (srow & 7);
    size_t goff = (size_t)srow * 1024 + gc * 8;
    int doff = wid * 1024;
    const bf16* bSrc = Bw + (size_t)nbp * 262144;

#define BSTAGE(half, buf, kt) do {                                             \
        const bf16* s_ = bSrc + (half) * 131072 + (size_t)(kt) * 64 + goff;    \
        char* d_ = smem + (buf) * 32768 + (half) * 16384 + doff;               \
        gload_lds16(s_, (bf16*)d_);                                            \
        gload_lds16(s_ + 65536, (bf16*)(d_ + 8192));                           \
    } while (0)

    // ---- B ds_read constants (swizzled chunks, 128B rows) ----
    int e0 = (q ^ (r & 7)) * 16, e1 = e0 ^ 64;

#define BREAD(dst, jh, bufb) do {                                              \
        _Pragma("unroll")                                                      \
        for (int jp = 0; jp < 2; jp++) {                                       \
            const char* pb_ = smem + (bufb) + (jh) * 16384                     \
                            + (wn * 32 + jp * 16 + r) * 128;                   \
            dst[jp * 2 + 0] = *(const bf16x8*)(pb_ + e0);                      \
            dst[jp * 2 + 1] = *(const bf16x8*)(pb_ + e1);                      \
        }                                                                      \
    } while (0)

    // ---- A register-direct: per-lane row pointer ----
    const bf16* aG = annb + (size_t)(mb * 256 + wm * 64 + r) * 1024 + q * 8;
    // frag(ih, ip, kt, ks) = aG + ih*131072 + ip*16384 + kt*64 + ks*32

#define ALOAD(dst, ih, kt) do {                                                \
        _Pragma("unroll")                                                      \
        for (int ip = 0; ip < 4; ip++) {                                       \
            const bf16* p_ = aG + (ih) * 131072 + ip * 16384 + (size_t)(kt) * 64; \
            dst[ip * 2 + 0] = *(const bf16x8*)(p_);                            \
            dst[ip * 2 + 1] = *(const bf16x8*)(p_ + 32);                       \
        }                                                                      \
    } while (0)

#define MM(IH, JH, aqv, bqv) do {                                              \
        __builtin_amdgcn_s_setprio(1);                                         \
        _Pragma("unroll")                                                      \
        for (int ip = 0; ip < 4; ip++)                                         \
            _Pragma("unroll")                                                  \
            for (int jp = 0; jp < 2; jp++)                                     \
                _Pragma("unroll")                                              \
                for (int ks = 0; ks < 2; ks++)                                 \
                    acc[(IH) * 4 + ip][(JH) * 2 + jp] =                        \
                        MFMA16x16x32(aqv[ip * 2 + ks], bqv[jp * 2 + ks],       \
                                     acc[(IH) * 4 + ip][(JH) * 2 + jp]);       \
        __builtin_amdgcn_s_setprio(0);                                         \
    } while (0)

    f32x4 acc[8][4];
#pragma unroll
    for (int i = 0; i < 8; i++)
#pragma unroll
        for (int j = 0; j < 4; j++) acc[i][j] = (f32x4)0.0f;

    bf16x8 aqc[8], aqn[8], bq0[4], bq1[4];

    // ---- prologue: B(0) -> buf0 ; AQC <- IH0(0) ----
    BSTAGE(0, 0, 0);
    BSTAGE(1, 0, 0);
    ALOAD(aqc, 0, 0);
    __builtin_amdgcn_sched_barrier(0);
    asm volatile("s_waitcnt vmcnt(8)" ::: "memory");   // drain B(0); A may fly
    __builtin_amdgcn_s_barrier();

#pragma unroll 1
    for (int kt = 0; kt < 16; kt++) {
        int curb = (kt & 1) * 32768, nxtb = curb ^ 32768;

        // pin B staging first (ledger: oldest vm ops this tile)
        if (kt < 15) { BSTAGE(0, (kt & 1) ^ 1, kt + 1);
                       BSTAGE(1, (kt & 1) ^ 1, kt + 1); }
        __builtin_amdgcn_sched_barrier(0);

        BREAD(bq0, 0, curb);
        ALOAD(aqn, 1, kt);                  // IH1(kt) in flight
        MM(0, 0, aqc, bq0);                 // P0

        BREAD(bq1, 1, curb);
        MM(0, 1, aqc, bq1);                 // P1 (aqc free after this)

        if (kt < 15) ALOAD(aqc, 0, kt + 1); // IH0(kt+1) in flight
        MM(1, 1, aqn, bq1);                 // P2 (compiler waits aqn)
        MM(1, 0, aqn, bq0);                 // P3

        __builtin_amdgcn_sched_barrier(0);
        asm volatile("s_waitcnt vmcnt(8)" ::: "memory"); // B(kt+1) drained
        __builtin_amdgcn_s_barrier();
    }
#undef MM
#undef ALOAD
#undef BREAD
#undef BSTAGE

    // fused epilogue: relu(hA + hB + b1) * W2, reduce over this block's n
    int m0 = mb * 256, n0g = nbp * 256;
    int b = m0 >> 9;                               // single batch per block
    float hb[4], w2v[4];
#pragma unroll
    for (int j = 0; j < 4; j++) {
        int n = n0g + (j >> 1) * 128 + wn * 32 + (j & 1) * 16 + r;
        float h = p_hB[b * Hh + n] + p_hB[65536 + b * Hh + n]
                + p_hB[131072 + b * Hh + n] + p_hB[196608 + b * Hh + n];
        hb[j]  = h + b1v[n];
        w2v[j] = W2[n];
    }
    float red[32];
#pragma unroll
    for (int i = 0; i < 8; i++)
#pragma unroll
        for (int rr = 0; rr < 4; rr++) {
            float s = 0.f;
#pragma unroll
            for (int j = 0; j < 4; j++) {
                float v = acc[i][j][rr] + hb[j];
                v = fmaxf(v, 0.f);
                s += v * w2v[j];
            }
            red[i * 4 + rr] = s;
        }
#pragma unroll
    for (int mask = 1; mask <= 8; mask <<= 1)
#pragma unroll
        for (int p = 0; p < 32; p++)
            red[p] += __shfl_xor(red[p], mask, 64);

    if (r == 0) {
        float* sp = scores_part + (size_t)(nbp * 4 + wn) * Mtot;
#pragma unroll
        for (int i = 0; i < 8; i++) {
            int m = m0 + wm * 64 + (i & 3) * 16 + (i >> 2) * 128 + q * 4;
#pragma unroll
            for (int rr = 0; rr < 4; rr++)
                sp[m + rr] = red[i * 4 + rr];
        }
    }
}

// ===========================================================================
// k_softmax: per b (64 blocks x 512 thr): sum 16 partials, softmax over s.
// ===========================================================================
__global__ void k_softmax(const float* __restrict__ scores_part, float* __restrict__ aw)
{
    int b = blockIdx.x, s = threadIdx.x;
    int lane = s & 63, wid = s >> 6;
    float v = 0.f;
#pragma unroll
    for (int p = 0; p < 16; p++) v += scores_part[(size_t)p * Mtot + b * Ss + s];

    __shared__ float redm[8], redsum[8];
    float m = v;
#pragma unroll
    for (int mask = 32; mask; mask >>= 1) m = fmaxf(m, __shfl_xor(m, mask, 64));
    if (lane == 0) redm[wid] = m;
    __syncthreads();
    float bm = redm[0];
#pragma unroll
    for (int w = 1; w < 8; w++) bm = fmaxf(bm, redm[w]);

    float e = expf(v - bm);
    float ss = e;
#pragma unroll
    for (int mask = 32; mask; mask >>= 1) ss += __shfl_xor(ss, mask, 64);
    if (lane == 0) redsum[wid] = ss;
    __syncthreads();
    float tot = 0.f;
#pragma unroll
    for (int w = 0; w < 8; w++) tot += redsum[w];

    aw[b * Ss + s] = e / tot;
}

// ===========================================================================
// k_context: ctx_part[sc][b][h] = sum_{s in 64-chunk} aw[b,s]*annb[b,s,h]
// ===========================================================================
__global__ void k_context(const bf16* __restrict__ annb, const float* __restrict__ aw,
                          float* __restrict__ ctx_part)
{
    __shared__ float law[64];
    int bid = blockIdx.x;
    int b = bid >> 3, sc = bid & 7;
    int t = threadIdx.x;
    if (t < 64) law[t] = aw[b * Ss + sc * 64 + t];
    __syncthreads();
    int h0 = t * 4;
    const bf16* ap = annb + (size_t)(b * Ss + sc * 64) * Hh + h0;
    float a0 = 0, a1 = 0, a2 = 0, a3 = 0;
#pragma unroll 4
    for (int s2 = 0; s2 < 64; s2++) {
        float w = law[s2];
        u32x2 v = *(const u32x2*)(ap + (size_t)s2 * Hh);
        a0 += w * bf2f((unsigned short)(v[0] & 0xffff));
        a1 += w * bf2f((unsigned short)(v[0] >> 16));
        a2 += w * bf2f((unsigned short)(v[1] & 0xffff));
        a3 += w * bf2f((unsigned short)(v[1] >> 16));
    }
    fx4 o; o[0] = a0; o[1] = a1; o[2] = a2; o[3] = a3;
    *(fx4*)(ctx_part + sc * 65536 + b * Hh + h0) = o;
}

// ===========================================================================
// k_xc: xc_b[:, 0:H] = bf16(sum of 8 ctx partials)
// ===========================================================================
__global__ void k_xc(const float* __restrict__ ctx_part, bf16* __restrict__ xc_b)
{
    int idx = blockIdx.x * 256 + threadIdx.x;          // 65536
    float c = 0.f;
#pragma unroll
    for (int p = 0; p < 8; p++) c += ctx_part[p * 65536 + idx];
    int b = idx >> 10, h = idx & 1023;
    xc_b[b * 2048 + h] = (bf16)c;
}

// ===========================================================================
// k_gru: gates + h_new (reads 4-way split-K partials)
// ===========================================================================
__global__ void k_gru(const float* __restrict__ p_iz, const float* __restrict__ p_ir,
                      const float* __restrict__ p_in, const float* __restrict__ p_hz,
                      const float* __restrict__ p_hn,
                      const float* __restrict__ b_iz, const float* __restrict__ b_ir,
                      const float* __restrict__ b_in, const float* __restrict__ b_hz,
                      const float* __restrict__ b_hn,
                      const float* __restrict__ h_prev,
                      float* __restrict__ out_h, bf16* __restrict__ h_new_b)
{
    int idx = blockIdx.x * 256 + threadIdx.x;          // 65536
    int o = idx & 1023;
    float iz = p_iz[idx] + p_iz[65536 + idx] + p_iz[131072 + idx] + p_iz[196608 + idx];
    float ir = p_ir[idx] + p_ir[65536 + idx] + p_ir[131072 + idx] + p_ir[196608 + idx];
    float in_ = p_in[idx] + p_in[65536 + idx] + p_in[131072 + idx] + p_in[196608 + idx];
    float hz = p_hz[idx] + p_hz[65536 + idx] + p_hz[131072 + idx] + p_hz[196608 + idx];
    float hn = p_hn[idx] + p_hn[65536 + idx] + p_hn[131072 + idx] + p_hn[196608 + idx];
    hz += b_hz[o];
    hn += b_hn[o];
    float z = 1.f / (1.f + expf(-(iz + b_iz[o] + hz)));
    float r = 1.f / (1.f + expf(-(ir + b_ir[o] + hz)));
    float g = tanhf(in_ + b_in[o] + r * hn);
    float hp = h_prev[idx];
    float hnew = (1.f - z) * g + z * hp;
    out_h[idx] = hnew;
    h_new_b[idx] = (bf16)hnew;
}

// ===========================================================================
extern "C" void kernel_launch(void* const* d_in, const int* in_sizes, int n_in,
                              void* d_out, int out_size, void* d_ws, size_t ws_size,
                              hipStream_t stream)
{
    const int*   x        = (const int*)d_in[0];
    const float* h_prev   = (const float*)d_in[1];
    const float* ann      = (const float*)d_in[2];
    const float* emb      = (const float*)d_in[3];
    const float* attn_W1  = (const float*)d_in[4];
    const float* attn_b1  = (const float*)d_in[5];
    const float* attn_W2  = (const float*)d_in[6];
    const float* W_ir     = (const float*)d_in[8];
    const float* b_ir     = (const float*)d_in[9];
    const float* W_iz     = (const float*)d_in[10];
    const float* b_iz     = (const float*)d_in[11];
    const float* W_in     = (const float*)d_in[12];
    const float* b_in     = (const float*)d_in[13];
    const float* W_hz     = (const float*)d_in[14];
    const float* b_hz     = (const float*)d_in[15];
    const float* W_hn     = (const float*)d_in[16];
    const float* b_hn     = (const float*)d_in[17];
    const float* W_out    = (const float*)d_in[18];
    const float* b_out    = (const float*)d_in[19];

    float* out = (float*)d_out;
    char*  ws  = (char*)d_ws;

    bf16*  h_new_b  = (bf16*)(ws + WS_HNEW_B);
    bf16*  xc_b     = (bf16*)(ws + WS_XC_B);
    bf16*  W1a_b    = (bf16*)(ws + WS_W1A_B);
    float* p_hB     = (float*)(ws + WS_P_HB);
    float* p_hz     = (float*)(ws + WS_P_HZ);
    float* p_hn     = (float*)(ws + WS_P_HN);
    float* p_iz     = (float*)(ws + WS_P_IZ);
    float* p_ir     = (float*)(ws + WS_P_IR);
    float* p_in     = (float*)(ws + WS_P_IN);
    float* scores_p = (float*)(ws + WS_SCORES);
    float* ctx_part = (float*)(ws + WS_CTX);
    bf16*  annb     = (bf16*)(ws + WS_ANNB);

    // allow dynamic LDS for k_attn (host-side attribute, capture-safe)
    (void)hipFuncSetAttribute(reinterpret_cast<const void*>(k_attn),
                              hipFuncAttributeMaxDynamicSharedMemorySize, 131072);

    // 1) merged pre-work: convann + prep + hB/hz/hn GEMMs (overlapped)
    k_pre<<<3328, 256, 0, stream>>>(x, h_prev, emb, attn_W1, W_hz, W_hn, ann,
                                    xc_b, W1a_b, annb, p_hB, p_hz, p_hn);

    // 2) fused attention GEMM -> 16 score partials
    k_attn<<<512, 512, 65536, stream>>>(annb, W1a_b, p_hB, attn_b1, attn_W2,
                                        scores_p);

    // 3) softmax -> attention weights (final output region)
    k_softmax<<<64, 512, 0, stream>>>(scores_p, out + OUT_AW);

    // 4) context = sum_s aw * annb  (8 s-chunks)
    k_context<<<512, 256, 0, stream>>>(annb, out + OUT_AW, ctx_part);

    // 5) xc = [context, embed] in bf16
    k_xc<<<256, 256, 0, stream>>>(ctx_part, xc_b);

    // 6) gate GEMMs (xc @ {W_iz, W_ir, W_in}^T), K=2048, split-K=4
    {
        dim3 g(16, 4, 3);
        k_sgemm<<<g, 256, 0, stream>>>(xc_b, 2048, 512,
                                       W_iz, W_ir, W_in, 2048, 2048, 2048,
                                       p_iz, p_ir, p_in, nullptr, 1024, 0);
    }

    // 7) GRU elementwise -> h_new (f32 out + bf16 ws)
    k_gru<<<256, 256, 0, stream>>>(p_iz, p_ir, p_in, p_hz, p_hn,
                                   b_iz, b_ir, b_in, b_hz, b_hn,
                                   h_prev, out + OUT_HNEW, h_new_b);

    // 8) output logits = h_new @ W_out^T + b_out
    {
        dim3 g(500, 1, 1);
        k_sgemm<<<g, 256, 0, stream>>>(h_new_b, 1024, 1024,
                                       W_out, W_out, W_out, 1024, 1024, 1024,
                                       out + OUT_LOGITS, nullptr, nullptr,
                                       b_out, 32000, 1);
    }
}

// Round 10
// 165.710 us; speedup vs baseline: 1.4336x; 1.4336x over previous
//
#include <hip/hip_runtime.h>

// ---------------------------------------------------------------------------
// AttentionDecoder: B=64, S=512, H=1024, V=32000
// outputs (f32, concat): output [64,32000] | h_new [64,1024] | attn_w [64,512]
// ---------------------------------------------------------------------------

typedef __bf16 bf16;
typedef __attribute__((ext_vector_type(4))) float  f32x4;
typedef __attribute__((ext_vector_type(4))) float  fx4;
typedef __attribute__((ext_vector_type(8))) bf16   bf16x8;
typedef __attribute__((ext_vector_type(4))) bf16   bf16x4;
typedef __attribute__((ext_vector_type(4))) unsigned int u32x4;
typedef __attribute__((ext_vector_type(2))) unsigned int u32x2;

#define MFMA16x16x32(a, b, c) __builtin_amdgcn_mfma_f32_16x16x32_bf16(a, b, c, 0, 0, 0)

#define Bb   64
#define Ss   512
#define Hh   1024
#define Vv   32000
#define Mtot (Bb * Ss)          // 32768

// ---- d_ws layout (bytes) --------------------------------------------------
#define WS_HNEW_B    131072                  // 64*1024 bf16   = 128KB
#define WS_XC_B      262144                  // 64*2048 bf16   = 256KB
#define WS_W1A_B     524288                  // 1024*1024 bf16 = 2MB
#define WS_P_HB      2621440                 // [4][64][1024] f32 = 1MB
#define WS_P_HZ      3670016
#define WS_P_HN      4718592
#define WS_P_IZ      5767168
#define WS_P_IR      6815744
#define WS_P_IN      7864320
#define WS_SCORES    8912896                 // [16][32768] f32 = 2MB
#define WS_CTX       11010048                // [8][64][1024] f32 = 2MB
#define WS_ANNB      13107200                // 32768*1024 bf16 = 64MB
// total ~80.3MB

// ---- d_out offsets (floats) ----------------------------------------------
#define OUT_LOGITS   0
#define OUT_HNEW     2048000
#define OUT_AW       2113536

__device__ __forceinline__ float bf2f(unsigned short u) {
    unsigned int x = ((unsigned int)u) << 16;
    float f;
    __builtin_memcpy(&f, &x, 4);
    return f;
}

// async global->LDS, 16B per lane. LDS dest is wave-uniform base; HW writes
// base + lane*16.
__device__ __forceinline__ void gload_lds16(const bf16* g, bf16* l)
{
    __builtin_amdgcn_global_load_lds(
        (const __attribute__((address_space(1))) unsigned int*)g,
        (__attribute__((address_space(3))) unsigned int*)l,
        16, 0, 0);
}

// ===========================================================================
// k_pre: merged pre-attention work, role-split grid (3328 blocks x 256):
//  [0,192)    : M=64 GEMM  p_hB/p_hz/p_hn = h_prev(f32) @ {W1b,W_hz,W_hn}^T
//  [192,1280) : prep: embed gather -> xc_b[:,H:2H] ; W1a -> bf16
//  [1280,3328): convann: ann f32 -> annb bf16 (201MB stream, hides the rest)
// ===========================================================================
__global__ __launch_bounds__(256, 2) void k_pre(
    const int* __restrict__ x, const float* __restrict__ h_prev,
    const float* __restrict__ emb, const float* __restrict__ attn_W1,
    const float* __restrict__ W_hz, const float* __restrict__ W_hn,
    const float* __restrict__ ann,
    bf16* __restrict__ xc_b, bf16* __restrict__ W1a_b, bf16* __restrict__ annb,
    float* __restrict__ p_hB, float* __restrict__ p_hz, float* __restrict__ p_hn)
{
    __shared__ __align__(16) bf16 lA[2][64][72];
    __shared__ __align__(16) bf16 lB[2][64][72];

    int bid = blockIdx.x, t = threadIdx.x;

    if (bid >= 1280) {
        // ---- convann ----
        size_t i = ((size_t)(bid - 1280) * 256 + t) * 8;
        size_t stride = (size_t)2048 * 256 * 8;
        size_t n = (size_t)Mtot * Hh;
        for (; i < n; i += stride) {
            fx4 v0 = *(const fx4*)(ann + i);
            fx4 v1 = *(const fx4*)(ann + i + 4);
            bf16x8 o;
#pragma unroll
            for (int q = 0; q < 4; q++) { o[q] = (bf16)v0[q]; o[q + 4] = (bf16)v1[q]; }
            *(bf16x8*)(annb + i) = o;
        }
        return;
    }
    if (bid >= 192) {
        // ---- prep ----
        int sub = bid - 192;
        if (sub < 64) {
            int b = sub, row = x[b];
            for (int i = t; i < Hh; i += 256)
                xc_b[b * 2048 + Hh + i] = (bf16)emb[(size_t)row * Hh + i];
        } else {
            int row = sub - 64;
            int k4 = t * 4;
            fx4 v = *(const fx4*)(attn_W1 + (size_t)row * 2048 + k4);
            bf16x4 o;
#pragma unroll
            for (int q = 0; q < 4; q++) o[q] = (bf16)v[q];
            *(bf16x4*)(W1a_b + (size_t)row * Hh + k4) = o;
        }
        return;
    }

    // ---- M=64 GEMM role (f32 A = h_prev) ----
    int nb = bid & 15, sk = (bid >> 4) & 3, mat = bid >> 6;
    const float* Bp = (mat == 0) ? (attn_W1 + 1024) : (mat == 1 ? W_hz : W_hn);
    int ldb         = (mat == 0) ? 2048 : 1024;
    float* op       = (mat == 0) ? p_hB : (mat == 1 ? p_hz : p_hn);

    int n0 = nb * 64, k0 = sk * 256;
    int lane = t & 63, wid = t >> 6;
    int srow = t >> 2, schunk = t & 3;

    const float* agp = h_prev + (size_t)srow * 1024 + k0 + schunk * 16;
    const float* bgp = Bp + (size_t)(n0 + srow) * ldb + k0 + schunk * 16;

    f32x4 acc[4];
#pragma unroll
    for (int i = 0; i < 4; i++) acc[i] = (f32x4)0.0f;

    fx4 aRf[4], bRf[4];
#pragma unroll
    for (int q = 0; q < 4; q++) { aRf[q] = *(const fx4*)(agp + q * 4);
                                  bRf[q] = *(const fx4*)(bgp + q * 4); }
    {
        bf16x8 a0, a1, p0, p1;
#pragma unroll
        for (int q = 0; q < 4; q++) {
            a0[q] = (bf16)aRf[0][q]; a0[q + 4] = (bf16)aRf[1][q];
            a1[q] = (bf16)aRf[2][q]; a1[q + 4] = (bf16)aRf[3][q];
            p0[q] = (bf16)bRf[0][q]; p0[q + 4] = (bf16)bRf[1][q];
            p1[q] = (bf16)bRf[2][q]; p1[q + 4] = (bf16)bRf[3][q];
        }
        *(bf16x8*)&lA[0][srow][schunk * 16]     = a0;
        *(bf16x8*)&lA[0][srow][schunk * 16 + 8] = a1;
        *(bf16x8*)&lB[0][srow][schunk * 16]     = p0;
        *(bf16x8*)&lB[0][srow][schunk * 16 + 8] = p1;
    }
    __syncthreads();

    int cur = 0;
    for (int ks = 0; ks < 4; ks++) {
        if (ks + 1 < 4) {
#pragma unroll
            for (int q = 0; q < 4; q++) {
                aRf[q] = *(const fx4*)(agp + (ks + 1) * 64 + q * 4);
                bRf[q] = *(const fx4*)(bgp + (ks + 1) * 64 + q * 4);
            }
        }
        int rA = lane & 15;
        int kc = (lane >> 4) * 8;
#pragma unroll
        for (int kk = 0; kk < 2; kk++) {
            bf16x8 bfr = *(bf16x8*)&lB[cur][wid * 16 + rA][kk * 32 + kc];
#pragma unroll
            for (int i = 0; i < 4; i++) {
                bf16x8 af = *(bf16x8*)&lA[cur][i * 16 + rA][kk * 32 + kc];
                acc[i] = MFMA16x16x32(af, bfr, acc[i]);
            }
        }
        if (ks + 1 < 4) {
            int nxt = cur ^ 1;
            bf16x8 a0, a1, p0, p1;
#pragma unroll
            for (int q = 0; q < 4; q++) {
                a0[q] = (bf16)aRf[0][q]; a0[q + 4] = (bf16)aRf[1][q];
                a1[q] = (bf16)aRf[2][q]; a1[q + 4] = (bf16)aRf[3][q];
                p0[q] = (bf16)bRf[0][q]; p0[q + 4] = (bf16)bRf[1][q];
                p1[q] = (bf16)bRf[2][q]; p1[q + 4] = (bf16)bRf[3][q];
            }
            *(bf16x8*)&lA[nxt][srow][schunk * 16]     = a0;
            *(bf16x8*)&lA[nxt][srow][schunk * 16 + 8] = a1;
            *(bf16x8*)&lB[nxt][srow][schunk * 16]     = p0;
            *(bf16x8*)&lB[nxt][srow][schunk * 16 + 8] = p1;
        }
        __syncthreads();
        cur ^= 1;
    }

    int n = n0 + wid * 16 + (lane & 15);
#pragma unroll
    for (int i = 0; i < 4; i++)
#pragma unroll
        for (int r = 0; r < 4; r++) {
            int m = i * 16 + (lane >> 4) * 4 + r;
            op[(size_t)(sk * 64 + m) * 1024 + n] = acc[i][r];
        }
}

// ===========================================================================
// k_sgemm: M=64 GEMM, out[m][n] = sum_k A_bf16[m][k] * (f32)Bmat[n][k]
// tile BM=64 BN=64 BK=64, 4 waves, dbuf reg-staged. (gates + W_out)
// ===========================================================================
__global__ __launch_bounds__(256, 2) void k_sgemm(
    const bf16* __restrict__ A, int lda, int kchunk,
    const float* __restrict__ B0, const float* __restrict__ B1, const float* __restrict__ B2,
    int ldb0, int ldb1, int ldb2,
    float* __restrict__ o0, float* __restrict__ o1, float* __restrict__ o2,
    const float* __restrict__ bias, int N, int finalOut)
{
    __shared__ __align__(16) bf16 lA[2][64][72];
    __shared__ __align__(16) bf16 lB[2][64][72];

    int nb = blockIdx.x, sk = blockIdx.y, mat = blockIdx.z;
    const float* Bp = (mat == 0) ? B0 : (mat == 1 ? B1 : B2);
    int ldb         = (mat == 0) ? ldb0 : (mat == 1 ? ldb1 : ldb2);
    float* op       = (mat == 0) ? o0 : (mat == 1 ? o1 : o2);

    int n0 = nb * 64, k0 = sk * kchunk;
    int t = threadIdx.x, lane = t & 63, wid = t >> 6;
    int srow = t >> 2, schunk = t & 3;

    const bf16*  agp = A  + (size_t)srow * lda + k0 + schunk * 16;
    const float* bgp = Bp + (size_t)(n0 + srow) * ldb + k0 + schunk * 16;

    f32x4 acc[4];
#pragma unroll
    for (int i = 0; i < 4; i++) acc[i] = (f32x4)0.0f;

    u32x4 aR0, aR1; fx4 bRf[4];
    int nk = kchunk >> 6;

    aR0 = *(const u32x4*)(agp);
    aR1 = *(const u32x4*)(agp + 8);
#pragma unroll
    for (int q = 0; q < 4; q++) bRf[q] = *(const fx4*)(bgp + q * 4);
    {
        *(u32x4*)&lA[0][srow][schunk * 16]     = aR0;
        *(u32x4*)&lA[0][srow][schunk * 16 + 8] = aR1;
        bf16x8 p0, p1;
#pragma unroll
        for (int q = 0; q < 4; q++) {
            p0[q] = (bf16)bRf[0][q]; p0[q + 4] = (bf16)bRf[1][q];
            p1[q] = (bf16)bRf[2][q]; p1[q + 4] = (bf16)bRf[3][q];
        }
        *(bf16x8*)&lB[0][srow][schunk * 16]     = p0;
        *(bf16x8*)&lB[0][srow][schunk * 16 + 8] = p1;
    }
    __syncthreads();

    int cur = 0;
    for (int ks = 0; ks < nk; ks++) {
        if (ks + 1 < nk) {
            aR0 = *(const u32x4*)(agp + (ks + 1) * 64);
            aR1 = *(const u32x4*)(agp + (ks + 1) * 64 + 8);
#pragma unroll
            for (int q = 0; q < 4; q++) bRf[q] = *(const fx4*)(bgp + (ks + 1) * 64 + q * 4);
        }
        int rA = lane & 15;
        int kc = (lane >> 4) * 8;
#pragma unroll
        for (int kk = 0; kk < 2; kk++) {
            bf16x8 bfr = *(bf16x8*)&lB[cur][wid * 16 + rA][kk * 32 + kc];
#pragma unroll
            for (int i = 0; i < 4; i++) {
                bf16x8 af = *(bf16x8*)&lA[cur][i * 16 + rA][kk * 32 + kc];
                acc[i] = MFMA16x16x32(af, bfr, acc[i]);
            }
        }
        if (ks + 1 < nk) {
            int nxt = cur ^ 1;
            *(u32x4*)&lA[nxt][srow][schunk * 16]     = aR0;
            *(u32x4*)&lA[nxt][srow][schunk * 16 + 8] = aR1;
            bf16x8 p0, p1;
#pragma unroll
            for (int q = 0; q < 4; q++) {
                p0[q] = (bf16)bRf[0][q]; p0[q + 4] = (bf16)bRf[1][q];
                p1[q] = (bf16)bRf[2][q]; p1[q + 4] = (bf16)bRf[3][q];
            }
            *(bf16x8*)&lB[nxt][srow][schunk * 16]     = p0;
            *(bf16x8*)&lB[nxt][srow][schunk * 16 + 8] = p1;
        }
        __syncthreads();
        cur ^= 1;
    }

    int n = n0 + wid * 16 + (lane & 15);
#pragma unroll
    for (int i = 0; i < 4; i++) {
#pragma unroll
        for (int r = 0; r < 4; r++) {
            int m = i * 16 + (lane >> 4) * 4 + r;
            float v = acc[i][r];
            if (finalOut) op[(size_t)m * N + n] = v + bias[n];
            else          op[(size_t)(sk * 64 + m) * N + n] = v;
        }
    }
}

// ===========================================================================
// k_attn v5 (reverted, best known: 75.5us): 256x256 tile, BK=32, 8 waves,
// QUAD-buffered LDS (4 x 32KB), stage kt+3 via global_load_lds, ONE raw
// s_barrier + counted vmcnt(8) per tile. 64B LDS rows; 12 ds_read + 32
// MFMA + 4 gloads per wave-tile.
// Fused epilogue: relu(hA+hB+b1)*W2 -> scores_part[nbp*4+wn][m].
// ===========================================================================
__global__ __launch_bounds__(512, 2) void k_attn(
    const bf16* __restrict__ annb, const bf16* __restrict__ Bw,
    const float* __restrict__ p_hB, const float* __restrict__ b1,
    const float* __restrict__ W2, float* __restrict__ scores_part)
{
    extern __shared__ char smem[];               // 4 x (A 16KB | B 16KB)

    int bid = blockIdx.x;
    int wgid = (bid & 7) * 64 + (bid >> 3);      // XCD-contiguous (512%8==0)
    int mb = wgid >> 2, nbp = wgid & 3;

    int t = threadIdx.x, lane = t & 63, wid = t >> 6;
    int wm = wid >> 2, wn = wid & 3;
    int r = lane & 15, q = lane >> 4;

    // staging: wave wid covers rows [wid*32, +32) in two 16-row calls.
    const bf16* aS = annb + (size_t)mb  * 262144
                   + (size_t)(wid * 32 + (lane >> 2)) * 1024 + (lane & 3) * 8;
    const bf16* bS = Bw   + (size_t)nbp * 262144
                   + (size_t)(wid * 32 + (lane >> 2)) * 1024 + (lane & 3) * 8;
    int sld = wid * 2048;                        // LDS byte offset (wave-uniform)

#define STAGE(kt) do { int bq_ = ((kt) & 3) * 32768;                         \
        const bf16* a_ = aS + (kt) * 32;                                     \
        const bf16* b_ = bS + (kt) * 32;                                     \
        gload_lds16(a_,         (bf16*)(smem + bq_ + sld));                  \
        gload_lds16(a_ + 16384, (bf16*)(smem + bq_ + sld + 1024));           \
        gload_lds16(b_,         (bf16*)(smem + bq_ + 16384 + sld));          \
        gload_lds16(b_ + 16384, (bf16*)(smem + bq_ + 16384 + sld + 1024));   \
    } while (0)

    // fragment read offsets (bytes within a buffer)
    int rAo[8], rBo[4];
#pragma unroll
    for (int i = 0; i < 8; i++)
        rAo[i] = (wm * 64 + (i & 3) * 16 + (i >> 2) * 128 + r) * 64 + q * 16;
#pragma unroll
    for (int j = 0; j < 4; j++)
        rBo[j] = 16384 + (wn * 32 + (j & 1) * 16 + (j >> 1) * 128 + r) * 64 + q * 16;

    f32x4 acc[8][4];
#pragma unroll
    for (int i = 0; i < 8; i++)
#pragma unroll
        for (int j = 0; j < 4; j++) acc[i][j] = (f32x4)0.0f;

    // prologue: tiles 0,1,2 in flight (12 gloads); wait tile0 (8 remain)
    STAGE(0); STAGE(1); STAGE(2);
    asm volatile("s_waitcnt vmcnt(8)" ::: "memory");
    __builtin_amdgcn_s_barrier();

#pragma unroll 1
    for (int kt = 0; kt < 32; kt++) {
        const char* base = smem + (kt & 3) * 32768;
        bf16x8 aq[8], bq[4];
#pragma unroll
        for (int i = 0; i < 8; i++) aq[i] = *(const bf16x8*)(base + rAo[i]);
#pragma unroll
        for (int j = 0; j < 4; j++) bq[j] = *(const bf16x8*)(base + rBo[j]);
        if (kt < 29) STAGE(kt + 3);

        __builtin_amdgcn_s_setprio(1);
#pragma unroll
        for (int i = 0; i < 8; i++)
#pragma unroll
            for (int j = 0; j < 4; j++)
                acc[i][j] = MFMA16x16x32(aq[i], bq[j], acc[i][j]);
        __builtin_amdgcn_s_setprio(0);

        if (kt < 29)       { asm volatile("s_waitcnt vmcnt(8)" ::: "memory"); }
        else if (kt == 29) { asm volatile("s_waitcnt vmcnt(4)" ::: "memory"); }
        else if (kt == 30) { asm volatile("s_waitcnt vmcnt(0)" ::: "memory"); }
        if (kt < 31) __builtin_amdgcn_s_barrier();
    }
#undef STAGE

    // fused epilogue: relu(hA + hB + b1) * W2, reduce over this block's n
    int m0 = mb * 256, n0g = nbp * 256;
    int b = m0 >> 9;                               // single batch per block
    float hb[4], w2v[4];
#pragma unroll
    for (int j = 0; j < 4; j++) {
        int n = n0g + (j >> 1) * 128 + wn * 32 + (j & 1) * 16 + r;
        float h = p_hB[b * Hh + n] + p_hB[65536 + b * Hh + n]
                + p_hB[131072 + b * Hh + n] + p_hB[196608 + b * Hh + n];
        hb[j]  = h + b1[n];
        w2v[j] = W2[n];
    }
    float red[32];
#pragma unroll
    for (int i = 0; i < 8; i++)
#pragma unroll
        for (int rr = 0; rr < 4; rr++) {
            float s = 0.f;
#pragma unroll
            for (int j = 0; j < 4; j++) {
                float v = acc[i][j][rr] + hb[j];
                v = fmaxf(v, 0.f);
                s += v * w2v[j];
            }
            red[i * 4 + rr] = s;
        }
#pragma unroll
    for (int mask = 1; mask <= 8; mask <<= 1)
#pragma unroll
        for (int p = 0; p < 32; p++)
            red[p] += __shfl_xor(red[p], mask, 64);

    if (r == 0) {
        float* sp = scores_part + (size_t)(nbp * 4 + wn) * Mtot;
#pragma unroll
        for (int i = 0; i < 8; i++) {
            int m = m0 + wm * 64 + (i & 3) * 16 + (i >> 2) * 128 + q * 4;
#pragma unroll
            for (int rr = 0; rr < 4; rr++)
                sp[m + rr] = red[i * 4 + rr];
        }
    }
}

// ===========================================================================
// k_context (softmax fused): grid 512 (b*8+sc) x 256.
// Each block recomputes the FULL softmax of batch b from the 16 score
// partials (deterministic same-order reduction -> identical tot in all 8
// blocks of a b); sc==0 blocks write aw output. Then computes its 64-s
// context partial.
// ===========================================================================
__global__ void k_context(const bf16* __restrict__ annb,
                          const float* __restrict__ scores_part,
                          float* __restrict__ aw_out, float* __restrict__ ctx_part)
{
    __shared__ float law[512];
    __shared__ float red[8];
    int bid = blockIdx.x;
    int b = bid >> 3, sc = bid & 7;
    int t = threadIdx.x;
    int lane = t & 63, wid = t >> 6;

    // ---- softmax over s = 0..511 (thread t owns s = t and t+256) ----
    float v0 = 0.f, v1 = 0.f;
#pragma unroll
    for (int p = 0; p < 16; p++) {
        v0 += scores_part[(size_t)p * Mtot + b * Ss + t];
        v1 += scores_part[(size_t)p * Mtot + b * Ss + t + 256];
    }
    float m = fmaxf(v0, v1);
#pragma unroll
    for (int mask = 32; mask; mask >>= 1) m = fmaxf(m, __shfl_xor(m, mask, 64));
    if (lane == 0) red[wid] = m;
    __syncthreads();
    float bm = fmaxf(fmaxf(red[0], red[1]), fmaxf(red[2], red[3]));
    float e0 = expf(v0 - bm), e1 = expf(v1 - bm);
    float ss = e0 + e1;
#pragma unroll
    for (int mask = 32; mask; mask >>= 1) ss += __shfl_xor(ss, mask, 64);
    if (lane == 0) red[4 + wid] = ss;
    __syncthreads();
    float tot = (red[4] + red[5]) + (red[6] + red[7]);
    float w0 = e0 / tot, w1 = e1 / tot;
    law[t] = w0; law[t + 256] = w1;
    if (sc == 0) {
        aw_out[b * Ss + t]       = w0;
        aw_out[b * Ss + t + 256] = w1;
    }
    __syncthreads();

    // ---- context partial over this block's 64-s chunk ----
    int h0 = t * 4;
    const bf16* ap = annb + (size_t)(b * Ss + sc * 64) * Hh + h0;
    float a0 = 0, a1 = 0, a2 = 0, a3 = 0;
#pragma unroll 4
    for (int s2 = 0; s2 < 64; s2++) {
        float w = law[sc * 64 + s2];
        u32x2 v = *(const u32x2*)(ap + (size_t)s2 * Hh);
        a0 += w * bf2f((unsigned short)(v[0] & 0xffff));
        a1 += w * bf2f((unsigned short)(v[0] >> 16));
        a2 += w * bf2f((unsigned short)(v[1] & 0xffff));
        a3 += w * bf2f((unsigned short)(v[1] >> 16));
    }
    fx4 o; o[0] = a0; o[1] = a1; o[2] = a2; o[3] = a3;
    *(fx4*)(ctx_part + sc * 65536 + b * Hh + h0) = o;
}

// ===========================================================================
// k_xc: xc_b[:, 0:H] = bf16(sum of 8 ctx partials)
// ===========================================================================
__global__ void k_xc(const float* __restrict__ ctx_part, bf16* __restrict__ xc_b)
{
    int idx = blockIdx.x * 256 + threadIdx.x;          // 65536
    float c = 0.f;
#pragma unroll
    for (int p = 0; p < 8; p++) c += ctx_part[p * 65536 + idx];
    int b = idx >> 10, h = idx & 1023;
    xc_b[b * 2048 + h] = (bf16)c;
}

// ===========================================================================
// k_gru: gates + h_new (reads 4-way split-K partials)
// ===========================================================================
__global__ void k_gru(const float* __restrict__ p_iz, const float* __restrict__ p_ir,
                      const float* __restrict__ p_in, const float* __restrict__ p_hz,
                      const float* __restrict__ p_hn,
                      const float* __restrict__ b_iz, const float* __restrict__ b_ir,
                      const float* __restrict__ b_in, const float* __restrict__ b_hz,
                      const float* __restrict__ b_hn,
                      const float* __restrict__ h_prev,
                      float* __restrict__ out_h, bf16* __restrict__ h_new_b)
{
    int idx = blockIdx.x * 256 + threadIdx.x;          // 65536
    int o = idx & 1023;
    float iz = p_iz[idx] + p_iz[65536 + idx] + p_iz[131072 + idx] + p_iz[196608 + idx];
    float ir = p_ir[idx] + p_ir[65536 + idx] + p_ir[131072 + idx] + p_ir[196608 + idx];
    float in_ = p_in[idx] + p_in[65536 + idx] + p_in[131072 + idx] + p_in[196608 + idx];
    float hz = p_hz[idx] + p_hz[65536 + idx] + p_hz[131072 + idx] + p_hz[196608 + idx];
    float hn = p_hn[idx] + p_hn[65536 + idx] + p_hn[131072 + idx] + p_hn[196608 + idx];
    hz += b_hz[o];
    hn += b_hn[o];
    float z = 1.f / (1.f + expf(-(iz + b_iz[o] + hz)));
    float r = 1.f / (1.f + expf(-(ir + b_ir[o] + hz)));
    float g = tanhf(in_ + b_in[o] + r * hn);
    float hp = h_prev[idx];
    float hnew = (1.f - z) * g + z * hp;
    out_h[idx] = hnew;
    h_new_b[idx] = (bf16)hnew;
}

// ===========================================================================
extern "C" void kernel_launch(void* const* d_in, const int* in_sizes, int n_in,
                              void* d_out, int out_size, void* d_ws, size_t ws_size,
                              hipStream_t stream)
{
    const int*   x        = (const int*)d_in[0];
    const float* h_prev   = (const float*)d_in[1];
    const float* ann      = (const float*)d_in[2];
    const float* emb      = (const float*)d_in[3];
    const float* attn_W1  = (const float*)d_in[4];
    const float* attn_b1  = (const float*)d_in[5];
    const float* attn_W2  = (const float*)d_in[6];
    const float* W_ir     = (const float*)d_in[8];
    const float* b_ir     = (const float*)d_in[9];
    const float* W_iz     = (const float*)d_in[10];
    const float* b_iz     = (const float*)d_in[11];
    const float* W_in     = (const float*)d_in[12];
    const float* b_in     = (const float*)d_in[13];
    const float* W_hz     = (const float*)d_in[14];
    const float* b_hz     = (const float*)d_in[15];
    const float* W_hn     = (const float*)d_in[16];
    const float* b_hn     = (const float*)d_in[17];
    const float* W_out    = (const float*)d_in[18];
    const float* b_out    = (const float*)d_in[19];

    float* out = (float*)d_out;
    char*  ws  = (char*)d_ws;

    bf16*  h_new_b  = (bf16*)(ws + WS_HNEW_B);
    bf16*  xc_b     = (bf16*)(ws + WS_XC_B);
    bf16*  W1a_b    = (bf16*)(ws + WS_W1A_B);
    float* p_hB     = (float*)(ws + WS_P_HB);
    float* p_hz     = (float*)(ws + WS_P_HZ);
    float* p_hn     = (float*)(ws + WS_P_HN);
    float* p_iz     = (float*)(ws + WS_P_IZ);
    float* p_ir     = (float*)(ws + WS_P_IR);
    float* p_in     = (float*)(ws + WS_P_IN);
    float* scores_p = (float*)(ws + WS_SCORES);
    float* ctx_part = (float*)(ws + WS_CTX);
    bf16*  annb     = (bf16*)(ws + WS_ANNB);

    // allow 128KB dynamic LDS for k_attn (host-side attribute, capture-safe)
    (void)hipFuncSetAttribute(reinterpret_cast<const void*>(k_attn),
                              hipFuncAttributeMaxDynamicSharedMemorySize, 131072);

    // 1) merged pre-work: convann + prep + hB/hz/hn GEMMs (overlapped)
    k_pre<<<3328, 256, 0, stream>>>(x, h_prev, emb, attn_W1, W_hz, W_hn, ann,
                                    xc_b, W1a_b, annb, p_hB, p_hz, p_hn);

    // 2) fused attention GEMM -> 16 score partials
    k_attn<<<512, 512, 131072, stream>>>(annb, W1a_b, p_hB, attn_b1, attn_W2,
                                         scores_p);

    // 3) softmax (recomputed per block) + context partials + aw output
    k_context<<<512, 256, 0, stream>>>(annb, scores_p, out + OUT_AW, ctx_part);

    // 4) xc = [context, embed] in bf16
    k_xc<<<256, 256, 0, stream>>>(ctx_part, xc_b);

    // 5) gate GEMMs (xc @ {W_iz, W_ir, W_in}^T), K=2048, split-K=4
    {
        dim3 g(16, 4, 3);
        k_sgemm<<<g, 256, 0, stream>>>(xc_b, 2048, 512,
                                       W_iz, W_ir, W_in, 2048, 2048, 2048,
                                       p_iz, p_ir, p_in, nullptr, 1024, 0);
    }

    // 6) GRU elementwise -> h_new (f32 out + bf16 ws)
    k_gru<<<256, 256, 0, stream>>>(p_iz, p_ir, p_in, p_hz, p_hn,
                                   b_iz, b_ir, b_in, b_hz, b_hn,
                                   h_prev, out + OUT_HNEW, h_new_b);

    // 7) output logits = h_new @ W_out^T + b_out
    {
        dim3 g(500, 1, 1);
        k_sgemm<<<g, 256, 0, stream>>>(h_new_b, 1024, 1024,
                                       W_out, W_out, W_out, 1024, 1024, 1024,
                                       out + OUT_LOGITS, nullptr, nullptr,
                                       b_out, 32000, 1);
    }
}